// Round 8
// baseline (401.283 us; speedup 1.0000x reference)
//
#include <hip/hip_runtime.h>
#include <hip/hip_fp16.h>
#include <math.h>

#define FIXLEN 30.0f
#define BETA   0.25f

typedef unsigned short u16;
typedef unsigned int   u32;
typedef unsigned long long u64;
typedef _Float16 half8 __attribute__((ext_vector_type(8)));
typedef float    f32x4 __attribute__((ext_vector_type(4)));

// ---------------- ws layout (bytes) ----------------
#define CST_OFF    0         // f[16]: 0=scale,1=inv_s,2=EPS2,3=maxNrm
#define ZMAX_OFF   1024      // f[1024]
#define EMAXL_OFF  8192      // f[2048]
#define EMAXE_OFF  16384     // f[2048]
#define E2_OFF     24576     // f[16384]
#define NRM2P_OFF  90112     // f[16384*4]
#define BESTN_OFF  352256    // i[16384]
#define PV1_OFF    416768    // u64[8*16384]
#define PVB2_OFF   1465344   // f[8*16384]
#define ZH_OFF     1989632   // half[16384*256]
#define EH_OFF     10378240  // half[16384*256]  -> total 18766848

__device__ inline u32 fkey(float d) {
    u32 b = __float_as_uint(d);
    return (b & 0x80000000u) ? ~b : (b | 0x80000000u);
}
__device__ inline float fdec(u32 k) {
    u32 b = (k & 0x80000000u) ? (k & 0x7FFFFFFFu) : ~k;
    return __uint_as_float(b);
}
__device__ inline void gl_lds16(const void* g, void* l) {
    __builtin_amdgcn_global_load_lds(
        (const __attribute__((address_space(1))) unsigned int*)g,
        (__attribute__((address_space(3))) unsigned int*)l, 16, 0, 0);
}

// ---------------- K1: emb -> fp16 plane + e2 + residual-norm maxes ----------------
__global__ void k_split_e(const float* __restrict__ emb, u16* __restrict__ eh,
                          float* __restrict__ e2, float* __restrict__ emaxl,
                          float* __restrict__ emaxe) {
    int gidx = blockIdx.x * 256 + threadIdx.x;   // grid = 2048
    int n = gidx >> 5;
    int c8 = (gidx & 31) * 8;
    const float* ep = emb + (size_t)n * 256 + c8;
    float4 v0 = *(const float4*)ep;
    float4 v1 = *(const float4*)(ep + 4);
    float vv[8] = {v0.x, v0.y, v0.z, v0.w, v1.x, v1.y, v1.z, v1.w};
    u32 pw[4];
    float s2 = 0.f, r2 = 0.f;
    #pragma unroll
    for (int k = 0; k < 4; ++k) {
        __half h0 = __float2half(vv[2 * k]);
        __half h1 = __float2half(vv[2 * k + 1]);
        float r0 = vv[2 * k] - __half2float(h0);
        float r1 = vv[2 * k + 1] - __half2float(h1);
        s2 = fmaf(vv[2 * k], vv[2 * k], s2);
        s2 = fmaf(vv[2 * k + 1], vv[2 * k + 1], s2);
        r2 = fmaf(r0, r0, r2);
        r2 = fmaf(r1, r1, r2);
        pw[k] = (u32)__half_as_ushort(h0) | ((u32)__half_as_ushort(h1) << 16);
    }
    *(uint4*)(eh + (size_t)n * 256 + c8) = make_uint4(pw[0], pw[1], pw[2], pw[3]);
    #pragma unroll
    for (int off = 16; off > 0; off >>= 1) {
        s2 += __shfl_down(s2, off, 32);
        r2 += __shfl_down(r2, off, 32);
    }
    __shared__ float L1[8], L2[8];
    if ((threadIdx.x & 31) == 0) {
        e2[n] = s2;
        L1[threadIdx.x >> 5] = r2;
        L2[threadIdx.x >> 5] = s2;
    }
    __syncthreads();
    if (threadIdx.x == 0) {
        float a = 0.f, bmax = 0.f;
        #pragma unroll
        for (int i = 0; i < 8; ++i) { a = fmaxf(a, L1[i]); bmax = fmaxf(bmax, L2[i]); }
        emaxl[blockIdx.x] = a;
        emaxe[blockIdx.x] = bmax;
    }
}

// ---------------- K2: z -> fp16(z/30) (transpose) + residual max + token-norm partials ----------------
__global__ void k_split_z(const float* __restrict__ z, u16* __restrict__ zh,
                          float* __restrict__ zmax_part, float* __restrict__ nrm2p) {
    int bi = blockIdx.x;                     // grid = 1024
    int b = bi >> 6, rest = bi & 63;
    int c0 = (rest >> 4) * 64, s0 = (rest & 15) * 64;
    int ctile = rest >> 4;
    __shared__ float ld[64][65];
    __shared__ float red2[64][4];
    __shared__ float red3[64][4];
    __shared__ float rmax[64];
    int tid = threadIdx.x;
    #pragma unroll
    for (int p = 0; p < 16; ++p) {
        int idx = p * 256 + tid;
        int cc = idx >> 6, ss = idx & 63;
        ld[cc][ss] = z[(size_t)b * 262144 + (size_t)(c0 + cc) * 1024 + s0 + ss];
    }
    __syncthreads();
    int ss2 = tid >> 2, cq = tid & 3;
    int t = b * 1024 + s0 + ss2;
    float r2 = 0.f, n2 = 0.f;
    u32 pk[8];
    #pragma unroll
    for (int k = 0; k < 8; ++k) pk[k] = 0;
    #pragma unroll
    for (int j = 0; j < 16; ++j) {
        float vr = ld[cq * 16 + j][ss2];
        n2 = fmaf(vr, vr, n2);
        float v = vr * (1.0f / 30.0f);
        __half h = __float2half(v);
        float r = v - __half2float(h);
        r2 = fmaf(r, r, r2);
        pk[j >> 1] |= ((u32)__half_as_ushort(h)) << ((j & 1) * 16);
    }
    u16* dst = zh + (size_t)t * 256 + c0 + cq * 16;
    *(uint4*)dst = make_uint4(pk[0], pk[1], pk[2], pk[3]);
    *(uint4*)(dst + 8) = make_uint4(pk[4], pk[5], pk[6], pk[7]);
    red2[ss2][cq] = r2;
    red3[ss2][cq] = n2;
    __syncthreads();
    if (tid < 64) {
        rmax[tid] = red2[tid][0] + red2[tid][1] + red2[tid][2] + red2[tid][3];
        float nn = red3[tid][0] + red3[tid][1] + red3[tid][2] + red3[tid][3];
        nrm2p[(size_t)(b * 1024 + s0 + tid) * 4 + ctile] = nn;
    }
    __syncthreads();
    for (int off = 32; off > 0; off >>= 1) {
        if (tid < off) rmax[tid] = fmaxf(rmax[tid], rmax[tid + off]);
        __syncthreads();
    }
    if (tid == 0) zmax_part[bi] = rmax[0];
}

// ---------------- K3: scalar pass: scale + maxNrm + EPS2 + zero diff accumulator ----------------
__global__ void k_scalars(const float* __restrict__ nrm2p, const float* __restrict__ zmax_part,
                          const float* __restrict__ emaxl, const float* __restrict__ emaxe,
                          float* __restrict__ cst, float* __restrict__ out) {
    int tid = threadIdx.x;  // 256
    float s = 0.f, m = 0.f;
    for (int i = tid; i < 16384; i += 256) {
        float4 v = *(const float4*)(nrm2p + (size_t)i * 4);
        float nr = sqrtf(v.x + v.y + v.z + v.w);
        s += nr;
        m = fmaxf(m, nr);
    }
    float zm = 0.f, el = 0.f, ee = 0.f;
    for (int i = tid; i < 1024; i += 256) zm = fmaxf(zm, zmax_part[i]);
    for (int i = tid; i < 2048; i += 256) { el = fmaxf(el, emaxl[i]); ee = fmaxf(ee, emaxe[i]); }
    __shared__ float S[256], M[256], Z[256], L[256], E[256];
    S[tid] = s; M[tid] = m; Z[tid] = zm; L[tid] = el; E[tid] = ee;
    __syncthreads();
    for (int off = 128; off > 0; off >>= 1) {
        if (tid < off) {
            S[tid] += S[tid + off];
            M[tid] = fmaxf(M[tid], M[tid + off]);
            Z[tid] = fmaxf(Z[tid], Z[tid + off]);
            L[tid] = fmaxf(L[tid], L[tid + off]);
            E[tid] = fmaxf(E[tid], E[tid + off]);
        }
        __syncthreads();
    }
    if (tid == 0) {
        float pre_len = S[0] * (1.0f / 16384.0f);
        float scale = (pre_len >= FIXLEN) ? (FIXLEN / pre_len) : 1.0f;
        cst[0] = scale;
        cst[1] = 1.0f / scale;
        cst[3] = M[0];
        float maxA  = M[0] * (1.0f / 30.0f);
        float maxEl = sqrtf(L[0]);
        float maxE  = sqrtf(E[0]);
        float maxZl = 2.0f * sqrtf(Z[0]);
        float eps = 2.0f * (maxA * maxEl + maxZl * maxE + maxZl * maxEl) + 0.03f;
        cst[2] = 2.0f * eps;
        out[4194304] = 0.f;     // diff accumulator (k_emit atomicAdd)
    }
}

// ---------------- K4: fp16 MFMA GEMM, 128 tok x 2048 emb per block, 64x128 wave tile ----------------
// LDS: resident token plane sA 64 KB @0 (identical layout/addresses to validated round-6 core)
//      + emb k-slice sB 16 KB @65536, k-major [4 k8-groups][256 rows] (conflict-free per phase model)
//      = 81920 B -> 2 blocks/CU. Merge arrays overlay sB at the end.
// ROUND-8 FIX: chunk stride in B staging is 256 rows * 256 k = 65536 u16 (was 32768 -> mislabeled rows).
__launch_bounds__(256, 2)
__global__ void k_mfma(const u16* __restrict__ zh, const u16* __restrict__ eh,
                       const float* __restrict__ e2g, const float* __restrict__ cst,
                       u64* __restrict__ pv1, float* __restrict__ pvb2) {
    __shared__ __align__(16) char lds[81920];
    char* sAb = lds;            // tokens [128 rows][256 k], 512B/row, low-3-bit slot XOR by row&7
    char* sBb = lds + 65536;    // embs k-major: slot k8 in 0..3 -> [k8*4096 + row*16]

    int part = blockIdx.x & 7;        // XCD-aligned: one 2048-emb slice per XCD L2
    int tokT = blockIdx.x >> 3;       // 0..127
    int t0 = tokT * 128;
    int nbase = part * 2048;
    float inv_s = cst[1];
    int tid = threadIdx.x, w = tid >> 6, lane = tid & 63;
    int ml = lane & 15, q = lane >> 4;
    int wm0 = (w & 1) * 64;           // token half
    int wn2 = (w >> 1) * 128;         // emb half within chunk
    int x7 = ml & 7;

    // stage resident token plane (identical to round-6): 4096 chunks, 16/thread
    #pragma unroll
    for (int i = 0; i < 16; ++i) {
        int el = i * 256 + tid;
        int row = el >> 5, j = el & 31;
        int jsrc = (j & 24) | ((j & 7) ^ (row & 7));
        gl_lds16(zh + (size_t)(t0 + row) * 256 + jsrc * 8, sAb + el * 16);
    }
    // B staging base: thread tid stages row tid of each chunk (4 k8-groups per ks)
    const u16* gB0 = eh + (size_t)(nbase + tid) * 256;

    float b1[16], b2[16]; int i1[16];
    #pragma unroll
    for (int k = 0; k < 16; ++k) { b1[k] = 3.4e38f; b2[k] = 3.4e38f; i1[k] = 0; }

    for (int chunk = 0; chunk < 8; ++chunk) {
        int nc = nbase + chunk * 256;

        f32x4 acc[4][8];
        #pragma unroll
        for (int i = 0; i < 4; ++i)
            #pragma unroll
            for (int j = 0; j < 8; ++j) acc[i][j] = (f32x4){0.f, 0.f, 0.f, 0.f};

        for (int ks = 0; ks < 8; ++ks) {
            __syncthreads();
            // stage emb slice (256 rows x 32 k): element (k8=i, row=tid)
            #pragma unroll
            for (int i = 0; i < 4; ++i)
                gl_lds16(gB0 + (size_t)chunk * 65536 + ks * 32 + i * 8,
                         sBb + i * 4096 + tid * 16);
            __syncthreads();

            int sl = ((ks & 1) * 4 + q) ^ x7;          // same addresses as round-6 A-read
            half8 A[4], B[8];
            #pragma unroll
            for (int ti = 0; ti < 4; ++ti)
                A[ti] = *(const half8*)(sAb + (wm0 + ti * 16 + ml) * 512 + ((ks >> 1) * 8 + sl) * 16);
            #pragma unroll
            for (int tj = 0; tj < 8; ++tj)
                B[tj] = *(const half8*)(sBb + q * 4096 + (wn2 + tj * 16 + ml) * 16);
            #pragma unroll
            for (int ti = 0; ti < 4; ++ti)
                #pragma unroll
                for (int tj = 0; tj < 8; ++tj)
                    acc[ti][tj] = __builtin_amdgcn_mfma_f32_16x16x32_f16(A[ti], B[tj], acc[ti][tj], 0, 0, 0);
        }
        // epilogue: d = e2*inv_s - 2*dot ; running top-2 per token-row
        float etv[8];
        #pragma unroll
        for (int tj = 0; tj < 8; ++tj) etv[tj] = e2g[nc + wn2 + tj * 16 + ml] * inv_s;
        #pragma unroll
        for (int tj = 0; tj < 8; ++tj) {
            int n = nc + wn2 + tj * 16 + ml;
            #pragma unroll
            for (int ti = 0; ti < 4; ++ti) {
                #pragma unroll
                for (int r = 0; r < 4; ++r) {
                    int k = ti * 4 + r;
                    float d = fmaf(-2.0f, acc[ti][tj][r], etv[tj]);
                    b2[k] = __builtin_amdgcn_fmed3f(b1[k], b2[k], d);   // running 2nd-min
                    bool c = d < b1[k];
                    b1[k] = fminf(b1[k], d);
                    i1[k] = c ? n : i1[k];
                }
            }
        }
    }

    // cross-lane merge over ml (masks 1..8); ties collapse b2->b1 -> refine path
    #pragma unroll
    for (int k = 0; k < 16; ++k) {
        #pragma unroll
        for (int m = 1; m < 16; m <<= 1) {
            float o1 = __shfl_xor(b1[k], m);
            int   oi = __shfl_xor(i1[k], m);
            float o2 = __shfl_xor(b2[k], m);
            float big = fmaxf(b1[k], o1);
            b2[k] = fminf(fminf(b2[k], o2), big);
            bool c = o1 < b1[k];
            i1[k] = c ? oi : i1[k];
            b1[k] = fminf(b1[k], o1);
        }
    }
    __syncthreads();   // all LDS compute reads done; overlay merge arrays on sB region
    float* m1s = (float*)sBb;            // [128]
    int*   mis = (int*)(sBb + 512);      // [128]
    float* m2s = (float*)(sBb + 1024);   // [128]
    if (w < 2 && ml == 0) {              // emb-half 0 writes
        #pragma unroll
        for (int ti = 0; ti < 4; ++ti)
            #pragma unroll
            for (int r = 0; r < 4; ++r) {
                int mr = wm0 + ti * 16 + q * 4 + r;
                int k = ti * 4 + r;
                m1s[mr] = b1[k]; mis[mr] = i1[k]; m2s[mr] = b2[k];
            }
    }
    __syncthreads();
    if (w >= 2 && ml == 0) {             // emb-half 1 merges + stores
        #pragma unroll
        for (int ti = 0; ti < 4; ++ti)
            #pragma unroll
            for (int r = 0; r < 4; ++r) {
                int mr = wm0 + ti * 16 + q * 4 + r;
                int k = ti * 4 + r;
                float a1 = m1s[mr]; int ai = mis[mr]; float a2 = m2s[mr];
                float f1, f2; int fi;
                if (a1 < b1[k]) { f1 = a1; fi = ai; f2 = fminf(a2, b1[k]); }
                else            { f1 = b1[k]; fi = i1[k]; f2 = fminf(b2[k], a1); }
                int t = t0 + mr;
                pv1[(size_t)part * 16384 + t] = ((u64)fkey(f1) << 32) | (u32)fi;
                pvb2[(size_t)part * 16384 + t] = f2;
            }
    }
}

// ---------------- K5: certify + exact-refine fused (per-block local list) ----------------
__global__ void k_refine(const float* __restrict__ z, const float* __restrict__ emb,
                         const float* __restrict__ e2, const u64* __restrict__ pv1,
                         const float* __restrict__ pvb2, const float* __restrict__ cst,
                         int* __restrict__ bestn) {
    __shared__ int llist[256];
    __shared__ int lcnt;
    __shared__ float az[4][256];
    int tid = threadIdx.x;
    if (tid == 0) lcnt = 0;
    __syncthreads();
    int t = blockIdx.x * 256 + tid;   // grid 64
    float EPS2 = cst[2], inv_s = cst[1];
    {
        float amin = 3.4e38f, sec = 3.4e38f; int wi = 0;
        #pragma unroll
        for (int p = 0; p < 8; ++p) {
            u64 u = pv1[(size_t)p * 16384 + t];
            float d1 = fdec((u32)(u >> 32));
            float d2 = pvb2[(size_t)p * 16384 + t];
            if (d1 < amin) { sec = fminf(fminf(sec, amin), d2); amin = d1; wi = (int)(u32)(u & 0xFFFFFFFFull); }
            else sec = fminf(sec, d1);
        }
        if (sec > amin + EPS2) bestn[t] = wi;
        else { int pos = atomicAdd(&lcnt, 1); llist[pos] = t; }
    }
    __syncthreads();
    int C = lcnt;
    int w = tid >> 6, lane = tid & 63;
    for (int it = w; it < C; it += 4) {
        int tt = llist[it];
        int b = tt >> 10, hw = tt & 1023;
        #pragma unroll
        for (int j = 0; j < 4; ++j)
            az[w][lane + 64 * j] = z[(size_t)b * 262144 + (size_t)(lane + 64 * j) * 1024 + hw] * (1.0f / 30.0f);
        float pb1[8], pb2[8]; int pi1[8];
        float amin = 3.4e38f;
        #pragma unroll
        for (int p = 0; p < 8; ++p) {
            u64 u = pv1[(size_t)p * 16384 + tt];
            pb1[p] = fdec((u32)(u >> 32));
            pi1[p] = (int)(u32)(u & 0xFFFFFFFFull);
            pb2[p] = pvb2[(size_t)p * 16384 + tt];
            amin = fminf(amin, pb1[p]);
        }
        float thresh = amin + EPS2;
        float bestv = 3.4e38f; int bi = 0x7fffffff;
        for (int p = 0; p < 8; ++p) {
            if (pb2[p] <= thresh) {
                // part may hide candidates beyond its top-2: full exact scan (rare)
                for (int it2 = 0; it2 < 32; ++it2) {
                    int n = p * 2048 + it2 * 64 + lane;
                    const float4* ep = (const float4*)(emb + (size_t)n * 256);
                    float s = 0.f;
                    #pragma unroll 16
                    for (int kk = 0; kk < 64; ++kk) {
                        float4 a4 = *(const float4*)&az[w][kk * 4];
                        float4 e4 = ep[kk];
                        s = fmaf(a4.x, e4.x, s); s = fmaf(a4.y, e4.y, s);
                        s = fmaf(a4.z, e4.z, s); s = fmaf(a4.w, e4.w, s);
                    }
                    float d = fmaf(-2.0f, s, e2[n] * inv_s);
                    if (d < bestv || (d == bestv && n < bi)) { bestv = d; bi = n; }
                }
            } else if (pb1[p] <= thresh) {
                // single candidate: exact distributed dot
                int n = pi1[p];
                float4 a4 = *(const float4*)&az[w][lane * 4];
                float4 e4 = *(const float4*)&emb[(size_t)n * 256 + lane * 4];
                float s = a4.x * e4.x + a4.y * e4.y + a4.z * e4.z + a4.w * e4.w;
                #pragma unroll
                for (int m = 1; m < 64; m <<= 1) s += __shfl_xor(s, m);
                float d = fmaf(-2.0f, s, e2[n] * inv_s);
                if (d < bestv || (d == bestv && n < bi)) { bestv = d; bi = n; }
            }
        }
        #pragma unroll
        for (int m = 1; m < 64; m <<= 1) {
            float ov = __shfl_xor(bestv, m);
            int oi = __shfl_xor(bi, m);
            if (ov < bestv || (ov == bestv && oi < bi)) { bestv = ov; bi = oi; }
        }
        if (lane == 0) bestn[tt] = bi;
    }
}

// ---------------- K6: emit z_q + idx + diff (fused atomic) ----------------
__global__ void k_emit(const float* __restrict__ z, const float* __restrict__ emb,
                       const float* __restrict__ cst, const int* __restrict__ bestn,
                       float* __restrict__ out) {
    int blk = blockIdx.x;                 // 512
    int cq = blk >> 6, sub = blk & 63;    // 8 channel-groups of 32
    int b = sub >> 2;
    int tl = (sub & 3) * 256 + threadIdx.x;
    int t = b * 1024 + tl;
    int bi = bestn[t];
    if (cq == 0) out[4194305 + t] = (float)bi;
    float scale = cst[0];
    const float* er = emb + (size_t)bi * 256 + cq * 32;
    const float* zr = z + (size_t)b * 262144 + (size_t)cq * 32768 + tl;
    float* orow = out + (size_t)b * 262144 + (size_t)cq * 32768 + tl;
    float ds = 0.f;
    #pragma unroll 8
    for (int j = 0; j < 32; ++j) {
        float qv = er[j] * FIXLEN;
        float zt = zr[(size_t)j << 10] * scale;
        float dd = qv - zt;
        ds = fmaf(dd, dd, ds);
        orow[(size_t)j << 10] = qv;
    }
    __shared__ float red[256];
    red[threadIdx.x] = ds;
    __syncthreads();
    for (int off = 128; off > 0; off >>= 1) {
        if (threadIdx.x < off) red[threadIdx.x] += red[threadIdx.x + off];
        __syncthreads();
    }
    if (threadIdx.x == 0) atomicAdd(out + 4194304, red[0] * (BETA / 4194304.0f));
}

extern "C" void kernel_launch(void* const* d_in, const int* in_sizes, int n_in,
                              void* d_out, int out_size, void* d_ws, size_t ws_size,
                              hipStream_t stream) {
    const float* z   = (const float*)d_in[0];
    const float* emb = (const float*)d_in[1];
    float* out = (float*)d_out;
    char* wsb = (char*)d_ws;

    float* cst       = (float*)(wsb + CST_OFF);
    float* zmax_part = (float*)(wsb + ZMAX_OFF);
    float* emaxl     = (float*)(wsb + EMAXL_OFF);
    float* emaxe     = (float*)(wsb + EMAXE_OFF);
    float* e2        = (float*)(wsb + E2_OFF);
    float* nrm2p     = (float*)(wsb + NRM2P_OFF);
    int*   bestn     = (int*)(wsb + BESTN_OFF);
    u64*   pv1       = (u64*)(wsb + PV1_OFF);
    float* pvb2      = (float*)(wsb + PVB2_OFF);
    u16*   zh        = (u16*)(wsb + ZH_OFF);
    u16*   eh        = (u16*)(wsb + EH_OFF);

    k_split_e<<<2048, 256, 0, stream>>>(emb, eh, e2, emaxl, emaxe);
    k_split_z<<<1024, 256, 0, stream>>>(z, zh, zmax_part, nrm2p);
    k_scalars<<<1, 256, 0, stream>>>(nrm2p, zmax_part, emaxl, emaxe, cst, out);
    k_mfma<<<1024, 256, 0, stream>>>(zh, eh, e2, cst, pv1, pvb2);
    k_refine<<<64, 256, 0, stream>>>(z, emb, e2, pv1, pvb2, cst, bestn);
    k_emit<<<512, 256, 0, stream>>>(z, emb, cst, bestn, out);
}

// Round 9
// 343.925 us; speedup vs baseline: 1.1668x; 1.1668x over previous
//
#include <hip/hip_runtime.h>
#include <hip/hip_fp16.h>
#include <math.h>

#define FIXLEN 30.0f
#define BETA   0.25f

typedef unsigned short u16;
typedef unsigned int   u32;
typedef unsigned long long u64;
typedef _Float16 half8 __attribute__((ext_vector_type(8)));
typedef float    f32x4 __attribute__((ext_vector_type(4)));

// ---------------- ws layout (bytes) ----------------
#define CST_OFF    0         // f[16]: 0=scale,1=inv_s,2=EPS2,3=maxNrm
#define ZMAX_OFF   1024      // f[1024]
#define EMAXL_OFF  8192      // f[2048]
#define EMAXE_OFF  16384     // f[2048]
#define E2_OFF     24576     // f[16384]
#define NRM2P_OFF  90112     // f[16384*4]
#define BESTN_OFF  352256    // i[16384]
#define PV1_OFF    416768    // u64[8*16384]
#define PVB2_OFF   1465344   // f[8*16384]
#define ZH_OFF     1989632   // half[16384*256]
#define EH_OFF     10378240  // half[16384*256], k8-interleaved: (n,k) -> [(k>>3)*131072 + n*8 + (k&7)]

__device__ inline u32 fkey(float d) {
    u32 b = __float_as_uint(d);
    return (b & 0x80000000u) ? ~b : (b | 0x80000000u);
}
__device__ inline float fdec(u32 k) {
    u32 b = (k & 0x80000000u) ? (k & 0x7FFFFFFFu) : ~k;
    return __uint_as_float(b);
}
__device__ inline void gl_lds16(const void* g, void* l) {
    __builtin_amdgcn_global_load_lds(
        (const __attribute__((address_space(1))) unsigned int*)g,
        (__attribute__((address_space(3))) unsigned int*)l, 16, 0, 0);
}

// ---------------- K1: emb -> fp16 plane (k8-interleaved) + e2 + residual-norm maxes ----------------
__global__ void k_split_e(const float* __restrict__ emb, u16* __restrict__ eh,
                          float* __restrict__ e2, float* __restrict__ emaxl,
                          float* __restrict__ emaxe) {
    int gidx = blockIdx.x * 256 + threadIdx.x;   // grid = 2048
    int n = gidx >> 5;
    int c8 = (gidx & 31) * 8;
    const float* ep = emb + (size_t)n * 256 + c8;
    float4 v0 = *(const float4*)ep;
    float4 v1 = *(const float4*)(ep + 4);
    float vv[8] = {v0.x, v0.y, v0.z, v0.w, v1.x, v1.y, v1.z, v1.w};
    u32 pw[4];
    float s2 = 0.f, r2 = 0.f;
    #pragma unroll
    for (int k = 0; k < 4; ++k) {
        __half h0 = __float2half(vv[2 * k]);
        __half h1 = __float2half(vv[2 * k + 1]);
        float r0 = vv[2 * k] - __half2float(h0);
        float r1 = vv[2 * k + 1] - __half2float(h1);
        s2 = fmaf(vv[2 * k], vv[2 * k], s2);
        s2 = fmaf(vv[2 * k + 1], vv[2 * k + 1], s2);
        r2 = fmaf(r0, r0, r2);
        r2 = fmaf(r1, r1, r2);
        pw[k] = (u32)__half_as_ushort(h0) | ((u32)__half_as_ushort(h1) << 16);
    }
    // k8-interleaved store: plane k8 = c8>>3, 16B per (n) row
    *(uint4*)(eh + (size_t)(c8 >> 3) * 131072 + (size_t)n * 8) = make_uint4(pw[0], pw[1], pw[2], pw[3]);
    #pragma unroll
    for (int off = 16; off > 0; off >>= 1) {
        s2 += __shfl_down(s2, off, 32);
        r2 += __shfl_down(r2, off, 32);
    }
    __shared__ float L1[8], L2[8];
    if ((threadIdx.x & 31) == 0) {
        e2[n] = s2;
        L1[threadIdx.x >> 5] = r2;
        L2[threadIdx.x >> 5] = s2;
    }
    __syncthreads();
    if (threadIdx.x == 0) {
        float a = 0.f, bmax = 0.f;
        #pragma unroll
        for (int i = 0; i < 8; ++i) { a = fmaxf(a, L1[i]); bmax = fmaxf(bmax, L2[i]); }
        emaxl[blockIdx.x] = a;
        emaxe[blockIdx.x] = bmax;
    }
}

// ---------------- K2: z -> fp16(z/30) (transpose) + residual max + token-norm partials ----------------
__global__ void k_split_z(const float* __restrict__ z, u16* __restrict__ zh,
                          float* __restrict__ zmax_part, float* __restrict__ nrm2p) {
    int bi = blockIdx.x;                     // grid = 1024
    int b = bi >> 6, rest = bi & 63;
    int c0 = (rest >> 4) * 64, s0 = (rest & 15) * 64;
    int ctile = rest >> 4;
    __shared__ float ld[64][65];
    __shared__ float red2[64][4];
    __shared__ float red3[64][4];
    __shared__ float rmax[64];
    int tid = threadIdx.x;
    #pragma unroll
    for (int p = 0; p < 16; ++p) {
        int idx = p * 256 + tid;
        int cc = idx >> 6, ss = idx & 63;
        ld[cc][ss] = z[(size_t)b * 262144 + (size_t)(c0 + cc) * 1024 + s0 + ss];
    }
    __syncthreads();
    int ss2 = tid >> 2, cq = tid & 3;
    int t = b * 1024 + s0 + ss2;
    float r2 = 0.f, n2 = 0.f;
    u32 pk[8];
    #pragma unroll
    for (int k = 0; k < 8; ++k) pk[k] = 0;
    #pragma unroll
    for (int j = 0; j < 16; ++j) {
        float vr = ld[cq * 16 + j][ss2];
        n2 = fmaf(vr, vr, n2);
        float v = vr * (1.0f / 30.0f);
        __half h = __float2half(v);
        float r = v - __half2float(h);
        r2 = fmaf(r, r, r2);
        pk[j >> 1] |= ((u32)__half_as_ushort(h)) << ((j & 1) * 16);
    }
    u16* dst = zh + (size_t)t * 256 + c0 + cq * 16;
    *(uint4*)dst = make_uint4(pk[0], pk[1], pk[2], pk[3]);
    *(uint4*)(dst + 8) = make_uint4(pk[4], pk[5], pk[6], pk[7]);
    red2[ss2][cq] = r2;
    red3[ss2][cq] = n2;
    __syncthreads();
    if (tid < 64) {
        rmax[tid] = red2[tid][0] + red2[tid][1] + red2[tid][2] + red2[tid][3];
        float nn = red3[tid][0] + red3[tid][1] + red3[tid][2] + red3[tid][3];
        nrm2p[(size_t)(b * 1024 + s0 + tid) * 4 + ctile] = nn;
    }
    __syncthreads();
    for (int off = 32; off > 0; off >>= 1) {
        if (tid < off) rmax[tid] = fmaxf(rmax[tid], rmax[tid + off]);
        __syncthreads();
    }
    if (tid == 0) zmax_part[bi] = rmax[0];
}

// ---------------- K3: scalar pass: scale + maxNrm + EPS2 + zero diff accumulator ----------------
__global__ void k_scalars(const float* __restrict__ nrm2p, const float* __restrict__ zmax_part,
                          const float* __restrict__ emaxl, const float* __restrict__ emaxe,
                          float* __restrict__ cst, float* __restrict__ out) {
    int tid = threadIdx.x;  // 256
    float s = 0.f, m = 0.f;
    for (int i = tid; i < 16384; i += 256) {
        float4 v = *(const float4*)(nrm2p + (size_t)i * 4);
        float nr = sqrtf(v.x + v.y + v.z + v.w);
        s += nr;
        m = fmaxf(m, nr);
    }
    float zm = 0.f, el = 0.f, ee = 0.f;
    for (int i = tid; i < 1024; i += 256) zm = fmaxf(zm, zmax_part[i]);
    for (int i = tid; i < 2048; i += 256) { el = fmaxf(el, emaxl[i]); ee = fmaxf(ee, emaxe[i]); }
    __shared__ float S[256], M[256], Z[256], L[256], E[256];
    S[tid] = s; M[tid] = m; Z[tid] = zm; L[tid] = el; E[tid] = ee;
    __syncthreads();
    for (int off = 128; off > 0; off >>= 1) {
        if (tid < off) {
            S[tid] += S[tid + off];
            M[tid] = fmaxf(M[tid], M[tid + off]);
            Z[tid] = fmaxf(Z[tid], Z[tid + off]);
            L[tid] = fmaxf(L[tid], L[tid + off]);
            E[tid] = fmaxf(E[tid], E[tid + off]);
        }
        __syncthreads();
    }
    if (tid == 0) {
        float pre_len = S[0] * (1.0f / 16384.0f);
        float scale = (pre_len >= FIXLEN) ? (FIXLEN / pre_len) : 1.0f;
        cst[0] = scale;
        cst[1] = 1.0f / scale;
        cst[3] = M[0];
        float maxA  = M[0] * (1.0f / 30.0f);
        float maxEl = sqrtf(L[0]);
        float maxE  = sqrtf(E[0]);
        float maxZl = 2.0f * sqrtf(Z[0]);
        float eps = 2.0f * (maxA * maxEl + maxZl * maxE + maxZl * maxEl) + 0.03f;
        cst[2] = 2.0f * eps;
        out[4194304] = 0.f;     // diff accumulator (k_emit atomicAdd)
    }
}

// ---------------- K4: fp16 MFMA GEMM, 128 tok x 2048 emb per block, 64x128 wave tile ----------------
// LDS: resident token plane sA 64 KB @0 + emb k-slice sB 16 KB @65536 (k-major [4 k8][256 rows])
//      = 81920 B -> 2 blocks/CU. Merge arrays overlay sB at the end.
// ROUND-9 FIX: eh stored k8-interleaved in global -> B-staging is 1 KB contiguous per wave instr
//              (round 8 read 64 scattered 16B lines per instr -> both pipes stalled at 19%).
__launch_bounds__(256, 2)
__global__ void k_mfma(const u16* __restrict__ zh, const u16* __restrict__ eh,
                       const float* __restrict__ e2g, const float* __restrict__ cst,
                       u64* __restrict__ pv1, float* __restrict__ pvb2) {
    __shared__ __align__(16) char lds[81920];
    char* sAb = lds;            // tokens [128 rows][256 k], 512B/row, low-3-bit slot XOR by row&7
    char* sBb = lds + 65536;    // embs k-major: [k8local*4096 + row*16]

    int part = blockIdx.x & 7;        // XCD-aligned: one 2048-emb slice per XCD L2
    int tokT = blockIdx.x >> 3;       // 0..127
    int t0 = tokT * 128;
    int nbase = part * 2048;
    float inv_s = cst[1];
    int tid = threadIdx.x, w = tid >> 6, lane = tid & 63;
    int ml = lane & 15, q = lane >> 4;
    int wm0 = (w & 1) * 64;           // token half
    int wn2 = (w >> 1) * 128;         // emb half within chunk
    int x7 = ml & 7;

    // stage resident token plane (identical to round-6): 4096 chunks, 16/thread
    #pragma unroll
    for (int i = 0; i < 16; ++i) {
        int el = i * 256 + tid;
        int row = el >> 5, j = el & 31;
        int jsrc = (j & 24) | ((j & 7) ^ (row & 7));
        gl_lds16(zh + (size_t)(t0 + row) * 256 + jsrc * 8, sAb + el * 16);
    }
    // B staging base in k8-interleaved eh: element (n = nbase+chunk*256+tid, k8 = ks*4+i)
    //   at eh[(ks*4+i)*131072 + n*8]; lanes (tid) are 16B-contiguous.
    const u16* gB0 = eh + (size_t)(nbase + tid) * 8;

    float b1[16], b2[16]; int i1[16];
    #pragma unroll
    for (int k = 0; k < 16; ++k) { b1[k] = 3.4e38f; b2[k] = 3.4e38f; i1[k] = 0; }

    for (int chunk = 0; chunk < 8; ++chunk) {
        int nc = nbase + chunk * 256;

        f32x4 acc[4][8];
        #pragma unroll
        for (int i = 0; i < 4; ++i)
            #pragma unroll
            for (int j = 0; j < 8; ++j) acc[i][j] = (f32x4){0.f, 0.f, 0.f, 0.f};

        for (int ks = 0; ks < 8; ++ks) {
            __syncthreads();
            // stage emb slice (256 rows x 32 k): plane k8 = ks*4+i, rows nc..nc+255
            #pragma unroll
            for (int i = 0; i < 4; ++i)
                gl_lds16(gB0 + (size_t)(ks * 4 + i) * 131072 + (size_t)chunk * 2048,
                         sBb + i * 4096 + tid * 16);
            __syncthreads();

            int sl = ((ks & 1) * 4 + q) ^ x7;          // same addresses as round-6 A-read
            half8 A[4], B[8];
            #pragma unroll
            for (int ti = 0; ti < 4; ++ti)
                A[ti] = *(const half8*)(sAb + (wm0 + ti * 16 + ml) * 512 + ((ks >> 1) * 8 + sl) * 16);
            #pragma unroll
            for (int tj = 0; tj < 8; ++tj)
                B[tj] = *(const half8*)(sBb + q * 4096 + (wn2 + tj * 16 + ml) * 16);
            #pragma unroll
            for (int ti = 0; ti < 4; ++ti)
                #pragma unroll
                for (int tj = 0; tj < 8; ++tj)
                    acc[ti][tj] = __builtin_amdgcn_mfma_f32_16x16x32_f16(A[ti], B[tj], acc[ti][tj], 0, 0, 0);
        }
        // epilogue: d = e2*inv_s - 2*dot ; running top-2 per token-row
        float etv[8];
        #pragma unroll
        for (int tj = 0; tj < 8; ++tj) etv[tj] = e2g[nc + wn2 + tj * 16 + ml] * inv_s;
        #pragma unroll
        for (int tj = 0; tj < 8; ++tj) {
            int n = nc + wn2 + tj * 16 + ml;
            #pragma unroll
            for (int ti = 0; ti < 4; ++ti) {
                #pragma unroll
                for (int r = 0; r < 4; ++r) {
                    int k = ti * 4 + r;
                    float d = fmaf(-2.0f, acc[ti][tj][r], etv[tj]);
                    b2[k] = __builtin_amdgcn_fmed3f(b1[k], b2[k], d);   // running 2nd-min
                    bool c = d < b1[k];
                    b1[k] = fminf(b1[k], d);
                    i1[k] = c ? n : i1[k];
                }
            }
        }
    }

    // cross-lane merge over ml (masks 1..8); ties collapse b2->b1 -> refine path
    #pragma unroll
    for (int k = 0; k < 16; ++k) {
        #pragma unroll
        for (int m = 1; m < 16; m <<= 1) {
            float o1 = __shfl_xor(b1[k], m);
            int   oi = __shfl_xor(i1[k], m);
            float o2 = __shfl_xor(b2[k], m);
            float big = fmaxf(b1[k], o1);
            b2[k] = fminf(fminf(b2[k], o2), big);
            bool c = o1 < b1[k];
            i1[k] = c ? oi : i1[k];
            b1[k] = fminf(b1[k], o1);
        }
    }
    __syncthreads();   // all LDS compute reads done; overlay merge arrays on sB region
    float* m1s = (float*)sBb;            // [128]
    int*   mis = (int*)(sBb + 512);      // [128]
    float* m2s = (float*)(sBb + 1024);   // [128]
    if (w < 2 && ml == 0) {              // emb-half 0 writes
        #pragma unroll
        for (int ti = 0; ti < 4; ++ti)
            #pragma unroll
            for (int r = 0; r < 4; ++r) {
                int mr = wm0 + ti * 16 + q * 4 + r;
                int k = ti * 4 + r;
                m1s[mr] = b1[k]; mis[mr] = i1[k]; m2s[mr] = b2[k];
            }
    }
    __syncthreads();
    if (w >= 2 && ml == 0) {             // emb-half 1 merges + stores
        #pragma unroll
        for (int ti = 0; ti < 4; ++ti)
            #pragma unroll
            for (int r = 0; r < 4; ++r) {
                int mr = wm0 + ti * 16 + q * 4 + r;
                int k = ti * 4 + r;
                float a1 = m1s[mr]; int ai = mis[mr]; float a2 = m2s[mr];
                float f1, f2; int fi;
                if (a1 < b1[k]) { f1 = a1; fi = ai; f2 = fminf(a2, b1[k]); }
                else            { f1 = b1[k]; fi = i1[k]; f2 = fminf(b2[k], a1); }
                int t = t0 + mr;
                pv1[(size_t)part * 16384 + t] = ((u64)fkey(f1) << 32) | (u32)fi;
                pvb2[(size_t)part * 16384 + t] = f2;
            }
    }
}

// ---------------- K5: certify + exact-refine fused (per-block local list) ----------------
__global__ void k_refine(const float* __restrict__ z, const float* __restrict__ emb,
                         const float* __restrict__ e2, const u64* __restrict__ pv1,
                         const float* __restrict__ pvb2, const float* __restrict__ cst,
                         int* __restrict__ bestn) {
    __shared__ int llist[256];
    __shared__ int lcnt;
    __shared__ float az[4][256];
    int tid = threadIdx.x;
    if (tid == 0) lcnt = 0;
    __syncthreads();
    int t = blockIdx.x * 256 + tid;   // grid 64
    float EPS2 = cst[2], inv_s = cst[1];
    {
        float amin = 3.4e38f, sec = 3.4e38f; int wi = 0;
        #pragma unroll
        for (int p = 0; p < 8; ++p) {
            u64 u = pv1[(size_t)p * 16384 + t];
            float d1 = fdec((u32)(u >> 32));
            float d2 = pvb2[(size_t)p * 16384 + t];
            if (d1 < amin) { sec = fminf(fminf(sec, amin), d2); amin = d1; wi = (int)(u32)(u & 0xFFFFFFFFull); }
            else sec = fminf(sec, d1);
        }
        if (sec > amin + EPS2) bestn[t] = wi;
        else { int pos = atomicAdd(&lcnt, 1); llist[pos] = t; }
    }
    __syncthreads();
    int C = lcnt;
    int w = tid >> 6, lane = tid & 63;
    for (int it = w; it < C; it += 4) {
        int tt = llist[it];
        int b = tt >> 10, hw = tt & 1023;
        #pragma unroll
        for (int j = 0; j < 4; ++j)
            az[w][lane + 64 * j] = z[(size_t)b * 262144 + (size_t)(lane + 64 * j) * 1024 + hw] * (1.0f / 30.0f);
        float pb1[8], pb2[8]; int pi1[8];
        float amin = 3.4e38f;
        #pragma unroll
        for (int p = 0; p < 8; ++p) {
            u64 u = pv1[(size_t)p * 16384 + tt];
            pb1[p] = fdec((u32)(u >> 32));
            pi1[p] = (int)(u32)(u & 0xFFFFFFFFull);
            pb2[p] = pvb2[(size_t)p * 16384 + tt];
            amin = fminf(amin, pb1[p]);
        }
        float thresh = amin + EPS2;
        float bestv = 3.4e38f; int bi = 0x7fffffff;
        for (int p = 0; p < 8; ++p) {
            if (pb2[p] <= thresh) {
                // part may hide candidates beyond its top-2: full exact scan (rare)
                for (int it2 = 0; it2 < 32; ++it2) {
                    int n = p * 2048 + it2 * 64 + lane;
                    const float4* ep = (const float4*)(emb + (size_t)n * 256);
                    float s = 0.f;
                    #pragma unroll 16
                    for (int kk = 0; kk < 64; ++kk) {
                        float4 a4 = *(const float4*)&az[w][kk * 4];
                        float4 e4 = ep[kk];
                        s = fmaf(a4.x, e4.x, s); s = fmaf(a4.y, e4.y, s);
                        s = fmaf(a4.z, e4.z, s); s = fmaf(a4.w, e4.w, s);
                    }
                    float d = fmaf(-2.0f, s, e2[n] * inv_s);
                    if (d < bestv || (d == bestv && n < bi)) { bestv = d; bi = n; }
                }
            } else if (pb1[p] <= thresh) {
                // single candidate: exact distributed dot
                int n = pi1[p];
                float4 a4 = *(const float4*)&az[w][lane * 4];
                float4 e4 = *(const float4*)&emb[(size_t)n * 256 + lane * 4];
                float s = a4.x * e4.x + a4.y * e4.y + a4.z * e4.z + a4.w * e4.w;
                #pragma unroll
                for (int m = 1; m < 64; m <<= 1) s += __shfl_xor(s, m);
                float d = fmaf(-2.0f, s, e2[n] * inv_s);
                if (d < bestv || (d == bestv && n < bi)) { bestv = d; bi = n; }
            }
        }
        #pragma unroll
        for (int m = 1; m < 64; m <<= 1) {
            float ov = __shfl_xor(bestv, m);
            int oi = __shfl_xor(bi, m);
            if (ov < bestv || (ov == bestv && oi < bi)) { bestv = ov; bi = oi; }
        }
        if (lane == 0) bestn[tt] = bi;
    }
}

// ---------------- K6: emit z_q + idx + diff (fused atomic) ----------------
__global__ void k_emit(const float* __restrict__ z, const float* __restrict__ emb,
                       const float* __restrict__ cst, const int* __restrict__ bestn,
                       float* __restrict__ out) {
    int blk = blockIdx.x;                 // 512
    int cq = blk >> 6, sub = blk & 63;    // 8 channel-groups of 32
    int b = sub >> 2;
    int tl = (sub & 3) * 256 + threadIdx.x;
    int t = b * 1024 + tl;
    int bi = bestn[t];
    if (cq == 0) out[4194305 + t] = (float)bi;
    float scale = cst[0];
    const float* er = emb + (size_t)bi * 256 + cq * 32;
    const float* zr = z + (size_t)b * 262144 + (size_t)cq * 32768 + tl;
    float* orow = out + (size_t)b * 262144 + (size_t)cq * 32768 + tl;
    float ds = 0.f;
    #pragma unroll 8
    for (int j = 0; j < 32; ++j) {
        float qv = er[j] * FIXLEN;
        float zt = zr[(size_t)j << 10] * scale;
        float dd = qv - zt;
        ds = fmaf(dd, dd, ds);
        orow[(size_t)j << 10] = qv;
    }
    __shared__ float red[256];
    red[threadIdx.x] = ds;
    __syncthreads();
    for (int off = 128; off > 0; off >>= 1) {
        if (threadIdx.x < off) red[threadIdx.x] += red[threadIdx.x + off];
        __syncthreads();
    }
    if (threadIdx.x == 0) atomicAdd(out + 4194304, red[0] * (BETA / 4194304.0f));
}

extern "C" void kernel_launch(void* const* d_in, const int* in_sizes, int n_in,
                              void* d_out, int out_size, void* d_ws, size_t ws_size,
                              hipStream_t stream) {
    const float* z   = (const float*)d_in[0];
    const float* emb = (const float*)d_in[1];
    float* out = (float*)d_out;
    char* wsb = (char*)d_ws;

    float* cst       = (float*)(wsb + CST_OFF);
    float* zmax_part = (float*)(wsb + ZMAX_OFF);
    float* emaxl     = (float*)(wsb + EMAXL_OFF);
    float* emaxe     = (float*)(wsb + EMAXE_OFF);
    float* e2        = (float*)(wsb + E2_OFF);
    float* nrm2p     = (float*)(wsb + NRM2P_OFF);
    int*   bestn     = (int*)(wsb + BESTN_OFF);
    u64*   pv1       = (u64*)(wsb + PV1_OFF);
    float* pvb2      = (float*)(wsb + PVB2_OFF);
    u16*   zh        = (u16*)(wsb + ZH_OFF);
    u16*   eh        = (u16*)(wsb + EH_OFF);

    k_split_e<<<2048, 256, 0, stream>>>(emb, eh, e2, emaxl, emaxe);
    k_split_z<<<1024, 256, 0, stream>>>(z, zh, zmax_part, nrm2p);
    k_scalars<<<1, 256, 0, stream>>>(nrm2p, zmax_part, emaxl, emaxe, cst, out);
    k_mfma<<<1024, 256, 0, stream>>>(zh, eh, e2, cst, pv1, pvb2);
    k_refine<<<64, 256, 0, stream>>>(z, emb, e2, pv1, pvb2, cst, bestn);
    k_emit<<<512, 256, 0, stream>>>(z, emb, cst, bestn, out);
}